// Round 7
// baseline (260.479 us; speedup 1.0000x reference)
//
#include <hip/hip_runtime.h>
#include <hip/hip_bf16.h>

#define M_ROWS 512
#define N_COLS 15080
#define N_PAD  15104           // 118*128
#define K_DIM  2048
#define BM 128
#define BN 128
#define BKF 64                 // K elements per k-step
#define NT 118                 // ceil(15080/128)
#define SCALE 20.0f            // 1/TEMP

#define KS 2                   // K-split factor
#define KSLICE (K_DIM / KS)    // 1024
#define KSTEPS_SK (KSLICE / BKF)  // 16

typedef _Float16 f16x8 __attribute__((ext_vector_type(8)));
typedef float    f32x4 __attribute__((ext_vector_type(4)));

// ===========================================================================
// PRIMARY PATH (split-K x2): 944 independent blocks.
// Round-4 evidence: 472-block grid pinned at ~284 TF regardless of waves/CU
// (occupancy 18.5->37% gave 0 gain) -> latency-bound on block count (m102
// curve: 256 blk=320 TF, 1024 blk=833 TF). Split-K doubles block count.
// Each block: 128x128 tile over K=1024, plain-stores raw partial scores.
// __launch_bounds__(256,2): 256-VGPR cap -- (256,4)'s 128 cap would force
// spill (need ~156: acc 64 + stage 32 + frags 40 + addr ~20).
// ===========================================================================
extern "C" __global__ __launch_bounds__(256, 2)
void k_gemm_sk(const float* __restrict__ A,    // features  [512][2048]
               const float* __restrict__ Bk,   // bank      [15080][2048]
               float* __restrict__ part)       // [KS][512][N_PAD] raw scores
{
    __shared__ __align__(16) ushort lds[16384];  // A plane 16K, B plane 16K (f16)

    const int t  = threadIdx.x;
    const int bx = blockIdx.x;

    // bijective XCD swizzle (944 = 8*118): same-(nt,ks) mi-quads get
    // consecutive wgid -> same XCD chunk; shared 512 KB B-slice L2-served 3x.
    const int wgid  = (bx & 7) * 118 + (bx >> 3);
    const int mi    = wgid & 3;
    const int group = wgid >> 2;        // 0..235
    const int nt    = group >> 1;
    const int ks    = group & 1;
    const int rowA0 = mi * BM;
    const int rowB0 = nt * BN;
    const int kbase = ks * KSLICE;
    float* outp = part + (size_t)ks * M_ROWS * N_PAD;

    // staging: 1024 16B-granules per plane / 256 threads = 4 each
    int arow[4], ag[4];
#pragma unroll
    for (int i = 0; i < 4; i++) { int G = t + i * 256; arow[i] = G >> 3; ag[i] = G & 7; }

    float4 ra[8], rb[8];
    auto LOAD = [&](int kt) {
#pragma unroll
        for (int i = 0; i < 4; i++) {
            const float* pa = A + (size_t)(rowA0 + arow[i]) * K_DIM + kbase + kt * BKF + ag[i] * 8;
            ra[2 * i]     = *(const float4*)(pa);
            ra[2 * i + 1] = *(const float4*)(pa + 4);
            const int br = rowB0 + arow[i];
            if (br < N_COLS) {
                const float* pb = Bk + (size_t)br * K_DIM + kbase + kt * BKF + ag[i] * 8;
                rb[2 * i]     = *(const float4*)(pb);
                rb[2 * i + 1] = *(const float4*)(pb + 4);
            } else {
                rb[2 * i]     = make_float4(0.f, 0.f, 0.f, 0.f);
                rb[2 * i + 1] = make_float4(0.f, 0.f, 0.f, 0.f);
            }
        }
    };
    auto STORE = [&]() {
#pragma unroll
        for (int i = 0; i < 4; i++) {
            const int ba = (arow[i] * 128 + ag[i] * 16) ^ ((arow[i] & 7) << 4);
            f16x8 ha, hb;
            float4 x = ra[2 * i], y = ra[2 * i + 1];
            ha[0] = (_Float16)x.x; ha[1] = (_Float16)x.y; ha[2] = (_Float16)x.z; ha[3] = (_Float16)x.w;
            ha[4] = (_Float16)y.x; ha[5] = (_Float16)y.y; ha[6] = (_Float16)y.z; ha[7] = (_Float16)y.w;
            x = rb[2 * i]; y = rb[2 * i + 1];
            hb[0] = (_Float16)x.x; hb[1] = (_Float16)x.y; hb[2] = (_Float16)x.z; hb[3] = (_Float16)x.w;
            hb[4] = (_Float16)y.x; hb[5] = (_Float16)y.y; hb[6] = (_Float16)y.z; hb[7] = (_Float16)y.w;
            *(f16x8*)((char*)lds + ba)         = ha;
            *(f16x8*)((char*)lds + 16384 + ba) = hb;
        }
    };

    // wave grid 2x2, wave tile 64x64, acc[4][4]
    const int lane = t & 63;
    const int wid  = t >> 6;
    const int wm = wid >> 1, wn = wid & 1;
    const int q = lane >> 4, r = lane & 15;
    int aaddr[4][2], baddr[4][2];
#pragma unroll
    for (int m = 0; m < 4; m++) {
        const int rowa = wm * 64 + m * 16 + r;
        const int rowb = wn * 64 + m * 16 + r;
#pragma unroll
        for (int kss = 0; kss < 2; kss++) {
            aaddr[m][kss] = (rowa * 128 + kss * 64 + q * 16) ^ ((rowa & 7) << 4);
            baddr[m][kss] = 16384 + ((rowb * 128 + kss * 64 + q * 16) ^ ((rowb & 7) << 4));
        }
    }

    f32x4 acc[4][4];
    const f32x4 zero = {0.f, 0.f, 0.f, 0.f};
#pragma unroll
    for (int m = 0; m < 4; m++)
#pragma unroll
        for (int n = 0; n < 4; n++) acc[m][n] = zero;

    LOAD(0);
    for (int kt = 0; kt < KSTEPS_SK; kt++) {
        __syncthreads();
        STORE();
        __syncthreads();
        if (kt + 1 < KSTEPS_SK) LOAD(kt + 1);

        f16x8 bf[4][2];
#pragma unroll
        for (int n = 0; n < 4; n++)
#pragma unroll
            for (int kss = 0; kss < 2; kss++)
                bf[n][kss] = *(const f16x8*)((const char*)lds + baddr[n][kss]);
#pragma unroll
        for (int m = 0; m < 4; m++) {
            const f16x8 af0 = *(const f16x8*)((const char*)lds + aaddr[m][0]);
            const f16x8 af1 = *(const f16x8*)((const char*)lds + aaddr[m][1]);
#pragma unroll
            for (int n = 0; n < 4; n++) {
                acc[m][n] = __builtin_amdgcn_mfma_f32_16x16x32_f16(af0, bf[n][0], acc[m][n], 0, 0, 0);
                acc[m][n] = __builtin_amdgcn_mfma_f32_16x16x32_f16(af1, bf[n][1], acc[m][n], 0, 0, 0);
            }
        }
    }

    // epilogue: plain stores of raw partial scores (C/D map: col=r, row=q*4+j)
#pragma unroll
    for (int m = 0; m < 4; m++)
#pragma unroll
        for (int j = 0; j < 4; j++) {
            const int grow = rowA0 + wm * 64 + m * 16 + q * 4 + j;
            float* rowp = outp + (size_t)grow * N_PAD + rowB0 + wn * 64 + r;
#pragma unroll
            for (int n = 0; n < 4; n++) rowp[n * 16] = acc[m][n][j];
        }
}

// ---------------------------------------------------------------------------
// k_lse: 512 blocks x 256 thr. Row b: online LSE over 20*(part0+part1),
// cols < 15080 only; subtract target logit.
// ---------------------------------------------------------------------------
extern "C" __global__ __launch_bounds__(256)
void k_lse(const float* __restrict__ part,
           const int*   __restrict__ gt,
           float* __restrict__ rowloss)
{
    const int b = blockIdx.x;
    const int t = threadIdx.x;
    __shared__ float lm[4], ls[4];

    const float4* p0 = (const float4*)(part + (size_t)b * N_PAD);
    const float4* p1 = (const float4*)(part + (size_t)(M_ROWS + b) * N_PAD);

    float m = -1e30f, s = 0.f;
    for (int c = t; c < 3770; c += 256) {          // 3770*4 = 15080 exactly
        const float4 a = p0[c], d = p1[c];
        const float x0 = SCALE * (a.x + d.x);
        const float x1 = SCALE * (a.y + d.y);
        const float x2 = SCALE * (a.z + d.z);
        const float x3 = SCALE * (a.w + d.w);
        const float mx = fmaxf(fmaxf(x0, x1), fmaxf(x2, x3));
        if (mx > m) { s *= __expf(m - mx); m = mx; }
        s += __expf(x0 - m) + __expf(x1 - m) + __expf(x2 - m) + __expf(x3 - m);
    }
#pragma unroll
    for (int d = 1; d < 64; d <<= 1) {
        const float om = __shfl_xor(m, d, 64);
        const float os = __shfl_xor(s, d, 64);
        const float nm = fmaxf(m, om);
        s = s * __expf(m - nm) + os * __expf(om - nm);
        m = nm;
    }
    if ((t & 63) == 0) { lm[t >> 6] = m; ls[t >> 6] = s; }
    __syncthreads();
    if (t == 0) {
        float M = fmaxf(fmaxf(lm[0], lm[1]), fmaxf(lm[2], lm[3]));
        float S = 0.f;
#pragma unroll
        for (int w = 0; w < 4; w++) S += ls[w] * __expf(lm[w] - M);
        const int pid = gt[b * 5 + 4];
        const float tgt = SCALE * (part[(size_t)b * N_PAD + pid] +
                                   part[(size_t)(M_ROWS + b) * N_PAD + pid]);
        rowloss[b] = M + logf(S) - tgt;
    }
}

extern "C" __global__ __launch_bounds__(512)
void k_final(const float* __restrict__ rowloss, float* __restrict__ out)
{
    __shared__ float red[512];
    const int b = threadIdx.x;
    red[b] = rowloss[b];
    __syncthreads();
    for (int s = 256; s > 0; s >>= 1) {
        if (b < s) red[b] += red[b + s];
        __syncthreads();
    }
    if (b == 0) out[0] = red[0] / 512.0f;
}

// ===========================================================================
// FALLBACK PATH (round-4, known-good, ~486 KB ws): used if ws_size < 62 MB.
// ===========================================================================
extern "C" __global__ __launch_bounds__(512, 4)
void k_gemm_lse(const float* __restrict__ A,
                const float* __restrict__ Bk,
                const int*   __restrict__ gt,
                float* __restrict__ pm,        // [512][NT]
                float* __restrict__ ps,        // [512][NT]
                float* __restrict__ tv)        // [512]
{
    __shared__ __align__(16) ushort lds[16384];

    const int t  = threadIdx.x;
    const int bx = blockIdx.x;
    int mi, nt;
    if (bx < 448) {
        const int slot = bx & 7;
        const int rest = bx >> 3;
        mi = rest & 3;
        nt = (rest >> 2) * 8 + slot;
    } else {
        const int r2 = bx - 448;
        mi = r2 & 3;
        nt = 112 + (r2 >> 2);
    }
    const int rowA0 = mi * BM;
    const int rowB0 = nt * BN;

    int arow[2], ag[2];
#pragma unroll
    for (int i = 0; i < 2; i++) { int G = t + i * 512; arow[i] = G >> 3; ag[i] = G & 7; }

    float4 ra[4], rb[4];
    auto LOAD = [&](int kt) {
#pragma unroll
        for (int i = 0; i < 2; i++) {
            const float* pa = A + (size_t)(rowA0 + arow[i]) * K_DIM + kt * BKF + ag[i] * 8;
            ra[2 * i]     = *(const float4*)(pa);
            ra[2 * i + 1] = *(const float4*)(pa + 4);
            const int br = rowB0 + arow[i];
            if (br < N_COLS) {
                const float* pb = Bk + (size_t)br * K_DIM + kt * BKF + ag[i] * 8;
                rb[2 * i]     = *(const float4*)(pb);
                rb[2 * i + 1] = *(const float4*)(pb + 4);
            } else {
                rb[2 * i]     = make_float4(0.f, 0.f, 0.f, 0.f);
                rb[2 * i + 1] = make_float4(0.f, 0.f, 0.f, 0.f);
            }
        }
    };
    auto STORE = [&]() {
#pragma unroll
        for (int i = 0; i < 2; i++) {
            const int ba = (arow[i] * 128 + ag[i] * 16) ^ ((arow[i] & 7) << 4);
            f16x8 ha, hb;
            float4 x = ra[2 * i], y = ra[2 * i + 1];
            ha[0] = (_Float16)x.x; ha[1] = (_Float16)x.y; ha[2] = (_Float16)x.z; ha[3] = (_Float16)x.w;
            ha[4] = (_Float16)y.x; ha[5] = (_Float16)y.y; ha[6] = (_Float16)y.z; ha[7] = (_Float16)y.w;
            x = rb[2 * i]; y = rb[2 * i + 1];
            hb[0] = (_Float16)x.x; hb[1] = (_Float16)x.y; hb[2] = (_Float16)x.z; hb[3] = (_Float16)x.w;
            hb[4] = (_Float16)y.x; hb[5] = (_Float16)y.y; hb[6] = (_Float16)y.z; hb[7] = (_Float16)y.w;
            *(f16x8*)((char*)lds + ba)         = ha;
            *(f16x8*)((char*)lds + 16384 + ba) = hb;
        }
    };

    const int lane = t & 63;
    const int wid  = t >> 6;
    const int wm = wid >> 2, wn = wid & 3;
    const int q = lane >> 4, r = lane & 15;
    int aaddr[4][2], baddr[2][2];
#pragma unroll
    for (int m = 0; m < 4; m++) {
        const int rowa = wm * 64 + m * 16 + r;
#pragma unroll
        for (int kss = 0; kss < 2; kss++)
            aaddr[m][kss] = (rowa * 128 + kss * 64 + q * 16) ^ ((rowa & 7) << 4);
    }
#pragma unroll
    for (int n = 0; n < 2; n++) {
        const int rowb = wn * 32 + n * 16 + r;
#pragma unroll
        for (int kss = 0; kss < 2; kss++)
            baddr[n][kss] = 16384 + ((rowb * 128 + kss * 64 + q * 16) ^ ((rowb & 7) << 4));
    }

    f32x4 acc[4][2];
    const f32x4 zero = {0.f, 0.f, 0.f, 0.f};
#pragma unroll
    for (int m = 0; m < 4; m++)
#pragma unroll
        for (int n = 0; n < 2; n++) acc[m][n] = zero;

    LOAD(0);
    for (int kt = 0; kt < (K_DIM / BKF); kt++) {
        __syncthreads();
        STORE();
        __syncthreads();
        if (kt + 1 < (K_DIM / BKF)) LOAD(kt + 1);

        f16x8 bf[2][2];
#pragma unroll
        for (int n = 0; n < 2; n++)
#pragma unroll
            for (int kss = 0; kss < 2; kss++)
                bf[n][kss] = *(const f16x8*)((const char*)lds + baddr[n][kss]);
#pragma unroll
        for (int m = 0; m < 4; m++) {
            const f16x8 af0 = *(const f16x8*)((const char*)lds + aaddr[m][0]);
            const f16x8 af1 = *(const f16x8*)((const char*)lds + aaddr[m][1]);
#pragma unroll
            for (int n = 0; n < 2; n++) {
                acc[m][n] = __builtin_amdgcn_mfma_f32_16x16x32_f16(af0, bf[n][0], acc[m][n], 0, 0, 0);
                acc[m][n] = __builtin_amdgcn_mfma_f32_16x16x32_f16(af1, bf[n][1], acc[m][n], 0, 0, 0);
            }
        }
    }

    __syncthreads();
    float* redm = (float*)lds;
    float* reds = ((float*)lds) + 512;

#pragma unroll
    for (int m = 0; m < 4; m++) {
#pragma unroll
        for (int j = 0; j < 4; j++) {
            const int lrow = wm * 64 + m * 16 + q * 4 + j;
            const int grow = rowA0 + lrow;
            const int pid  = gt[grow * 5 + 4];
            float sv[2];
            float mx = -INFINITY;
#pragma unroll
            for (int n = 0; n < 2; n++) {
                const int gc = rowB0 + wn * 32 + n * 16 + r;
                float s = SCALE * acc[m][n][j];
                s = (gc < N_COLS) ? s : -INFINITY;
                sv[n] = s;
                mx = fmaxf(mx, s);
                if (gc == pid) tv[grow] = s;
            }
#pragma unroll
            for (int d = 1; d < 16; d <<= 1) mx = fmaxf(mx, __shfl_xor(mx, d, 16));
            float se = 0.f;
#pragma unroll
            for (int n = 0; n < 2; n++) se += __expf(sv[n] - mx);
#pragma unroll
            for (int d = 1; d < 16; d <<= 1) se += __shfl_xor(se, d, 16);
            if (r == 0) { redm[wn * 128 + lrow] = mx; reds[wn * 128 + lrow] = se; }
        }
    }
    __syncthreads();
    if (t < 128) {
        float Mv = -INFINITY;
#pragma unroll
        for (int c = 0; c < 4; c++) Mv = fmaxf(Mv, redm[c * 128 + t]);
        float Sv = 0.f;
#pragma unroll
        for (int c = 0; c < 4; c++) Sv += reds[c * 128 + t] * __expf(redm[c * 128 + t] - Mv);
        pm[(rowA0 + t) * NT + nt] = Mv;
        ps[(rowA0 + t) * NT + nt] = Sv;
    }
}

extern "C" __global__ __launch_bounds__(128)
void k_rowlse(const float* __restrict__ pm,
              const float* __restrict__ ps,
              const float* __restrict__ tv,
              float* __restrict__ rowloss)
{
    const int b = blockIdx.x;
    const int i = threadIdx.x;
    __shared__ float wred[4];

    const float m = (i < NT) ? pm[b * NT + i] : -INFINITY;
    const float s = (i < NT) ? ps[b * NT + i] : 0.f;

    float M = m;
#pragma unroll
    for (int d = 1; d < 64; d <<= 1) M = fmaxf(M, __shfl_xor(M, d, 64));
    if ((i & 63) == 0) wred[i >> 6] = M;
    __syncthreads();
    M = fmaxf(wred[0], wred[1]);
    __syncthreads();

    float e = (i < NT) ? s * __expf(m - M) : 0.f;
#pragma unroll
    for (int d = 1; d < 64; d <<= 1) e += __shfl_xor(e, d, 64);
    if ((i & 63) == 0) wred[i >> 6] = e;
    __syncthreads();
    if (i == 0) {
        const float S = wred[0] + wred[1];
        rowloss[b] = M + logf(S) - tv[b];
    }
}

// ===========================================================================
extern "C" void kernel_launch(void* const* d_in, const int* in_sizes, int n_in,
                              void* d_out, int out_size, void* d_ws, size_t ws_size,
                              hipStream_t stream)
{
    const float* feat = (const float*)d_in[0];   // features (512,2048)
    const int*   gt   = (const int*)d_in[2];     // gt_labels (512,5)
    const float* bank = (const float*)d_in[4];   // bank_features (15080,2048)

    const size_t need = (size_t)KS * M_ROWS * N_PAD * 4 + 512 * 4;  // ~61.9 MB
    if (ws_size >= need) {
        float* part = (float*)d_ws;                       // [2][512][N_PAD]
        float* rl   = part + (size_t)KS * M_ROWS * N_PAD; // [512]
        k_gemm_sk<<<dim3(8 * NT), 256, 0, stream>>>(feat, bank, part);
        k_lse<<<dim3(M_ROWS), 256, 0, stream>>>(part, gt, rl);
        k_final<<<dim3(1), 512, 0, stream>>>(rl, (float*)d_out);
    } else {
        float* pm = (float*)d_ws;            // [512][NT]
        float* ps = pm + 512 * NT;           // [512][NT]
        float* tv = ps + 512 * NT;           // [512]
        float* rl = tv + 512;                // [512]
        k_gemm_lse<<<dim3(4 * NT), 512, 0, stream>>>(feat, bank, gt, pm, ps, tv);
        k_rowlse<<<dim3(512), 128, 0, stream>>>(pm, ps, tv, rl);
        k_final<<<dim3(1), 512, 0, stream>>>(rl, (float*)d_out);
    }
}

// Round 8
// 239.463 us; speedup vs baseline: 1.0878x; 1.0878x over previous
//
#include <hip/hip_runtime.h>
#include <hip/hip_bf16.h>

#define M_ROWS 512
#define N_COLS 15080
#define K_DIM  2048
#define BM 128
#define BN 128
#define BKF 64                   // K elements per k-step
#define NT 118                   // ceil(15080/128)
#define KSTEPS 32                // 2048/64
#define SCALE 20.0f              // 1/TEMP

#define BANK_PAD_ROWS 15104      // 118*128 (rows 15080..15103 zero-filled)
#define BANK_PAD_E (30932992ull) // 15104*2048
#define FEAT_E     (1048576ull)  // 512*2048
#define NG_CVT     (3997696ull)  // (BANK_PAD_E+FEAT_E)/8

typedef _Float16 f16x8 __attribute__((ext_vector_type(8)));
typedef float    f32x4 __attribute__((ext_vector_type(4)));

#define GLD_LDS16(gp, lp) __builtin_amdgcn_global_load_lds( \
    (const __attribute__((address_space(1))) void*)(gp),    \
    (__attribute__((address_space(3))) void*)(lp), 16, 0, 0)

// ---------------------------------------------------------------------------
// k_cvt: fp32 -> fp16 pre-pass. out = [bank16 padded 15104x2048][feat16 512x2048].
// Streaming, 8 elems/thread/iter, grid-stride. Pad rows zero-filled.
// ---------------------------------------------------------------------------
extern "C" __global__ __launch_bounds__(256)
void k_cvt(const float* __restrict__ feat, const float* __restrict__ bank,
           _Float16* __restrict__ out)
{
    const size_t stride = (size_t)gridDim.x * 256;
    for (size_t g = (size_t)blockIdx.x * 256 + threadIdx.x; g < NG_CVT; g += stride) {
        const size_t e = g * 8;
        f16x8 h;
        if (e < BANK_PAD_E) {
            const int row = (int)(e >> 11);
            if (row < N_COLS) {
                const float4 x = *(const float4*)(bank + e);
                const float4 y = *(const float4*)(bank + e + 4);
                h[0] = (_Float16)x.x; h[1] = (_Float16)x.y; h[2] = (_Float16)x.z; h[3] = (_Float16)x.w;
                h[4] = (_Float16)y.x; h[5] = (_Float16)y.y; h[6] = (_Float16)y.z; h[7] = (_Float16)y.w;
            } else {
                h = (f16x8)(_Float16)0.0f;
            }
        } else {
            const size_t e2 = e - BANK_PAD_E;
            const float4 x = *(const float4*)(feat + e2);
            const float4 y = *(const float4*)(feat + e2 + 4);
            h[0] = (_Float16)x.x; h[1] = (_Float16)x.y; h[2] = (_Float16)x.z; h[3] = (_Float16)x.w;
            h[4] = (_Float16)y.x; h[5] = (_Float16)y.y; h[6] = (_Float16)y.z; h[7] = (_Float16)y.w;
        }
        *(f16x8*)(out + e) = h;
    }
}

// ---------------------------------------------------------------------------
// k_gemm16: 472 blocks x 256 thr (4 waves, 2x2). 128x128 tile, K=2048.
// global_load_lds (16B) staging of fp16 with pre-swizzled SOURCE addresses
// (LDS linear per m104; swizzle g^(row&7) applied on the per-lane global
// address, m173 pattern) + double-buffered LDS (2x32KB), 2-phase pipeline:
// STAGE(kt+1 -> other buf) || COMPUTE(cur buf); one barrier per k-step.
// Fused per-tile LSE partials epilogue (round-4 verified).
// ---------------------------------------------------------------------------
extern "C" __global__ __launch_bounds__(256, 2)
void k_gemm16(const _Float16* __restrict__ A16,  // feat16 [512][2048]
              const _Float16* __restrict__ B16,  // bank16 [15104][2048]
              const int*      __restrict__ gt,
              float* __restrict__ pm,            // [512][NT]
              float* __restrict__ ps,            // [512][NT]
              float* __restrict__ tv)            // [512]
{
    __shared__ __align__(16) char lds[65536];    // 2 x (A 16K | B 16K)

    const int t  = threadIdx.x;
    const int bx = blockIdx.x;

    // XCD co-location swizzle (round-4): same-nt mi-quads congruent mod 8.
    int mi, nt;
    if (bx < 448) { const int slot = bx & 7; const int rest = bx >> 3;
                    mi = rest & 3; nt = (rest >> 2) * 8 + slot; }
    else          { const int r2 = bx - 448; mi = r2 & 3; nt = 112 + (r2 >> 2); }
    const int rowA0 = mi * BM;
    const int rowB0 = nt * BN;

    // ---- staging geometry: wave w stages chunks w*4..w*4+3 of each plane.
    // chunk = 8 rows x 128B; lane l -> (lr = l>>3, gg = l&7); source granule
    // gsrc = gg ^ lr  (pre-swizzle; row&7 == lr since chunks are 8-row-aligned)
    const int lane = t & 63, w = t >> 6;
    const int lr = lane >> 3, gg = lane & 7;
    const size_t aE0 = (size_t)(rowA0 + w * 32 + lr) * K_DIM + (size_t)((gg ^ lr) * 8);
    const size_t bE0 = (size_t)(rowB0 + w * 32 + lr) * K_DIM + (size_t)((gg ^ lr) * 8);
    const char* aP0 = (const char*)(A16 + aE0);
    const char* bP0 = (const char*)(B16 + bE0);
    const int ldsW = w * 4096;                    // wave's first chunk offset

    auto STAGE = [&](int kt, int sel) {
        const int   dofs = sel * 32768;
        const size_t ko  = (size_t)kt * 128;      // 64 f16 per k-step
#pragma unroll
        for (int j = 0; j < 4; j++) {             // +j*8 rows = +j*32768 B src
            GLD_LDS16(aP0 + (size_t)j * 32768 + ko, lds + dofs + ldsW + j * 1024);
            GLD_LDS16(bP0 + (size_t)j * 32768 + ko, lds + dofs + 16384 + ldsW + j * 1024);
        }
    };

    // ---- fragment read addresses (byte offsets within a buffer) ----
    const int wm = w >> 1, wn = w & 1;
    const int q = lane >> 4, r = lane & 15;
    int aaddr[4][2], baddr[4][2];
#pragma unroll
    for (int m = 0; m < 4; m++) {
        const int rowa = wm * 64 + m * 16 + r;
        const int rowb = wn * 64 + m * 16 + r;
#pragma unroll
        for (int ks = 0; ks < 2; ks++) {
            aaddr[m][ks] = (rowa * 128 + ks * 64 + q * 16) ^ ((rowa & 7) << 4);
            baddr[m][ks] = 16384 + ((rowb * 128 + ks * 64 + q * 16) ^ ((rowb & 7) << 4));
        }
    }

    f32x4 acc[4][4];
    const f32x4 zero = {0.f, 0.f, 0.f, 0.f};
#pragma unroll
    for (int m = 0; m < 4; m++)
#pragma unroll
        for (int n = 0; n < 4; n++) acc[m][n] = zero;

    auto COMPUTE = [&](int sel) {
        const char* bb = lds + sel * 32768;
        f16x8 bf[4][2];
#pragma unroll
        for (int n = 0; n < 4; n++)
#pragma unroll
            for (int ks = 0; ks < 2; ks++)
                bf[n][ks] = *(const f16x8*)(bb + baddr[n][ks]);
#pragma unroll
        for (int m = 0; m < 4; m++) {
            const f16x8 af0 = *(const f16x8*)(bb + aaddr[m][0]);
            const f16x8 af1 = *(const f16x8*)(bb + aaddr[m][1]);
#pragma unroll
            for (int n = 0; n < 4; n++) {
                acc[m][n] = __builtin_amdgcn_mfma_f32_16x16x32_f16(af0, bf[n][0], acc[m][n], 0, 0, 0);
                acc[m][n] = __builtin_amdgcn_mfma_f32_16x16x32_f16(af1, bf[n][1], acc[m][n], 0, 0, 0);
            }
        }
    };

    STAGE(0, 0);
    __syncthreads();                 // vmcnt(0) drain + barrier: buf0 ready
#pragma unroll 2
    for (int kt = 0; kt < KSTEPS - 1; kt++) {
        STAGE(kt + 1, (kt + 1) & 1); // async loads into other buffer
        COMPUTE(kt & 1);             // MFMA on current buffer (hides loads)
        __syncthreads();             // drains vmcnt(0): next buffer ready
    }
    COMPUTE((KSTEPS - 1) & 1);

    // ---------------- epilogue: fused per-tile LSE partials ----------------
    __syncthreads();
    float* redm = (float*)lds;               // [2][128]
    float* reds = ((float*)lds) + 256;       // [2][128]

#pragma unroll
    for (int m = 0; m < 4; m++) {
#pragma unroll
        for (int j = 0; j < 4; j++) {
            const int lrow = wm * 64 + m * 16 + q * 4 + j;
            const int grow = rowA0 + lrow;
            const int pid  = gt[grow * 5 + 4];
            float sv[4];
            float mx = -INFINITY;
#pragma unroll
            for (int n = 0; n < 4; n++) {
                const int gc = rowB0 + wn * 64 + n * 16 + r;
                float s = SCALE * acc[m][n][j];
                s = (gc < N_COLS) ? s : -INFINITY;
                sv[n] = s;
                mx = fmaxf(mx, s);
                if (gc == pid) tv[grow] = s;   // unique writer across grid
            }
#pragma unroll
            for (int d = 1; d < 16; d <<= 1) mx = fmaxf(mx, __shfl_xor(mx, d, 16));
            float se = 0.f;
#pragma unroll
            for (int n = 0; n < 4; n++) se += __expf(sv[n] - mx);
#pragma unroll
            for (int d = 1; d < 16; d <<= 1) se += __shfl_xor(se, d, 16);
            if (r == 0) { redm[wn * 128 + lrow] = mx; reds[wn * 128 + lrow] = se; }
        }
    }
    __syncthreads();
    if (t < 128) {
        const float m0 = redm[t], m1 = redm[128 + t];
        const float s0 = reds[t], s1 = reds[128 + t];
        const float Mv = fmaxf(m0, m1);
        const float Sv = s0 * __expf(m0 - Mv) + s1 * __expf(m1 - Mv);
        pm[(rowA0 + t) * NT + nt] = Mv;      // [row][NT] -> coalesced tail
        ps[(rowA0 + t) * NT + nt] = Sv;
    }
}

// ---------------------------------------------------------------------------
// k_rowlse: 512 blocks x 128 thr; merge row's NT partials -> LSE - target.
// ---------------------------------------------------------------------------
extern "C" __global__ __launch_bounds__(128)
void k_rowlse(const float* __restrict__ pm,
              const float* __restrict__ ps,
              const float* __restrict__ tv,
              float* __restrict__ rowloss)
{
    const int b = blockIdx.x;
    const int i = threadIdx.x;
    __shared__ float wred[4];

    const float m = (i < NT) ? pm[b * NT + i] : -INFINITY;
    const float s = (i < NT) ? ps[b * NT + i] : 0.f;

    float M = m;
#pragma unroll
    for (int d = 1; d < 64; d <<= 1) M = fmaxf(M, __shfl_xor(M, d, 64));
    if ((i & 63) == 0) wred[i >> 6] = M;
    __syncthreads();
    M = fmaxf(wred[0], wred[1]);
    __syncthreads();

    float e = (i < NT) ? s * __expf(m - M) : 0.f;
#pragma unroll
    for (int d = 1; d < 64; d <<= 1) e += __shfl_xor(e, d, 64);
    if ((i & 63) == 0) wred[i >> 6] = e;
    __syncthreads();
    if (i == 0) {
        const float S = wred[0] + wred[1];
        rowloss[b] = M + logf(S) - tv[b];
    }
}

extern "C" __global__ __launch_bounds__(512)
void k_final(const float* __restrict__ rowloss, float* __restrict__ out)
{
    __shared__ float red[512];
    const int b = threadIdx.x;
    red[b] = rowloss[b];
    __syncthreads();
    for (int s = 256; s > 0; s >>= 1) {
        if (b < s) red[b] += red[b + s];
        __syncthreads();
    }
    if (b == 0) out[0] = red[0] / 512.0f;
}

// ===========================================================================
// FALLBACK (round-4 known-good, ~486 KB ws): used if ws_size < 64.5 MB.
// ===========================================================================
extern "C" __global__ __launch_bounds__(512, 4)
void k_gemm_lse(const float* __restrict__ A,
                const float* __restrict__ Bk,
                const int*   __restrict__ gt,
                float* __restrict__ pm, float* __restrict__ ps,
                float* __restrict__ tv)
{
    __shared__ __align__(16) ushort lds[16384];
    const int t  = threadIdx.x;
    const int bx = blockIdx.x;
    int mi, nt;
    if (bx < 448) { const int slot = bx & 7; const int rest = bx >> 3;
                    mi = rest & 3; nt = (rest >> 2) * 8 + slot; }
    else          { const int r2 = bx - 448; mi = r2 & 3; nt = 112 + (r2 >> 2); }
    const int rowA0 = mi * BM, rowB0 = nt * BN;

    int arow[2], ag[2];
#pragma unroll
    for (int i = 0; i < 2; i++) { int G = t + i * 512; arow[i] = G >> 3; ag[i] = G & 7; }
    float4 ra[4], rb[4];
    auto LOAD = [&](int kt) {
#pragma unroll
        for (int i = 0; i < 2; i++) {
            const float* pa = A + (size_t)(rowA0 + arow[i]) * K_DIM + kt * BKF + ag[i] * 8;
            ra[2*i] = *(const float4*)(pa); ra[2*i+1] = *(const float4*)(pa + 4);
            const int br = rowB0 + arow[i];
            if (br < N_COLS) {
                const float* pb = Bk + (size_t)br * K_DIM + kt * BKF + ag[i] * 8;
                rb[2*i] = *(const float4*)(pb); rb[2*i+1] = *(const float4*)(pb + 4);
            } else { rb[2*i] = make_float4(0,0,0,0); rb[2*i+1] = make_float4(0,0,0,0); }
        }
    };
    auto STORE = [&]() {
#pragma unroll
        for (int i = 0; i < 2; i++) {
            const int ba = (arow[i] * 128 + ag[i] * 16) ^ ((arow[i] & 7) << 4);
            f16x8 ha, hb;
            float4 x = ra[2*i], y = ra[2*i+1];
            ha[0]=(_Float16)x.x; ha[1]=(_Float16)x.y; ha[2]=(_Float16)x.z; ha[3]=(_Float16)x.w;
            ha[4]=(_Float16)y.x; ha[5]=(_Float16)y.y; ha[6]=(_Float16)y.z; ha[7]=(_Float16)y.w;
            x = rb[2*i]; y = rb[2*i+1];
            hb[0]=(_Float16)x.x; hb[1]=(_Float16)x.y; hb[2]=(_Float16)x.z; hb[3]=(_Float16)x.w;
            hb[4]=(_Float16)y.x; hb[5]=(_Float16)y.y; hb[6]=(_Float16)y.z; hb[7]=(_Float16)y.w;
            *(f16x8*)((char*)lds + ba) = ha;
            *(f16x8*)((char*)lds + 16384 + ba) = hb;
        }
    };
    const int lane = t & 63, wid = t >> 6;
    const int wm = wid >> 2, wn = wid & 3;
    const int q = lane >> 4, r = lane & 15;
    int aaddr[4][2], baddr[2][2];
#pragma unroll
    for (int m = 0; m < 4; m++) { const int rowa = wm*64 + m*16 + r;
#pragma unroll
        for (int ks = 0; ks < 2; ks++) aaddr[m][ks] = (rowa*128 + ks*64 + q*16) ^ ((rowa&7)<<4); }
#pragma unroll
    for (int n = 0; n < 2; n++) { const int rowb = wn*32 + n*16 + r;
#pragma unroll
        for (int ks = 0; ks < 2; ks++) baddr[n][ks] = 16384 + ((rowb*128 + ks*64 + q*16) ^ ((rowb&7)<<4)); }

    f32x4 acc[4][2];
    const f32x4 zero = {0.f,0.f,0.f,0.f};
#pragma unroll
    for (int m = 0; m < 4; m++)
#pragma unroll
        for (int n = 0; n < 2; n++) acc[m][n] = zero;

    LOAD(0);
    for (int kt = 0; kt < KSTEPS; kt++) {
        __syncthreads(); STORE(); __syncthreads();
        if (kt + 1 < KSTEPS) LOAD(kt + 1);
        f16x8 bf[2][2];
#pragma unroll
        for (int n = 0; n < 2; n++)
#pragma unroll
            for (int ks = 0; ks < 2; ks++) bf[n][ks] = *(const f16x8*)((const char*)lds + baddr[n][ks]);
#pragma unroll
        for (int m = 0; m < 4; m++) {
            const f16x8 af0 = *(const f16x8*)((const char*)lds + aaddr[m][0]);
            const f16x8 af1 = *(const f16x8*)((const char*)lds + aaddr[m][1]);
#pragma unroll
            for (int n = 0; n < 2; n++) {
                acc[m][n] = __builtin_amdgcn_mfma_f32_16x16x32_f16(af0, bf[n][0], acc[m][n], 0,0,0);
                acc[m][n] = __builtin_amdgcn_mfma_f32_16x16x32_f16(af1, bf[n][1], acc[m][n], 0,0,0);
            }
        }
    }
    __syncthreads();
    float* redm = (float*)lds;
    float* reds = ((float*)lds) + 512;
#pragma unroll
    for (int m = 0; m < 4; m++) {
#pragma unroll
        for (int j = 0; j < 4; j++) {
            const int lrow = wm*64 + m*16 + q*4 + j;
            const int grow = rowA0 + lrow;
            const int pid  = gt[grow*5 + 4];
            float sv[2]; float mx = -INFINITY;
#pragma unroll
            for (int n = 0; n < 2; n++) {
                const int gc = rowB0 + wn*32 + n*16 + r;
                float s = SCALE * acc[m][n][j];
                s = (gc < N_COLS) ? s : -INFINITY;
                sv[n] = s; mx = fmaxf(mx, s);
                if (gc == pid) tv[grow] = s;
            }
#pragma unroll
            for (int d = 1; d < 16; d <<= 1) mx = fmaxf(mx, __shfl_xor(mx, d, 16));
            float se = 0.f;
#pragma unroll
            for (int n = 0; n < 2; n++) se += __expf(sv[n] - mx);
#pragma unroll
            for (int d = 1; d < 16; d <<= 1) se += __shfl_xor(se, d, 16);
            if (r == 0) { redm[wn*128 + lrow] = mx; reds[wn*128 + lrow] = se; }
        }
    }
    __syncthreads();
    if (t < 128) {
        float Mv = -INFINITY;
#pragma unroll
        for (int c = 0; c < 4; c++) Mv = fmaxf(Mv, redm[c*128 + t]);
        float Sv = 0.f;
#pragma unroll
        for (int c = 0; c < 4; c++) Sv += reds[c*128 + t] * __expf(redm[c*128 + t] - Mv);
        pm[(rowA0 + t) * NT + nt] = Mv;
        ps[(rowA0 + t) * NT + nt] = Sv;
    }
}

// ===========================================================================
extern "C" void kernel_launch(void* const* d_in, const int* in_sizes, int n_in,
                              void* d_out, int out_size, void* d_ws, size_t ws_size,
                              hipStream_t stream)
{
    const float* feat = (const float*)d_in[0];   // features (512,2048)
    const int*   gt   = (const int*)d_in[2];     // gt_labels (512,5)
    const float* bank = (const float*)d_in[4];   // bank_features (15080,2048)

    // primary ws layout: bank16 | feat16 | pm | ps | tv | rl
    const size_t NEED = (BANK_PAD_E + FEAT_E) * 2 + (size_t)512 * NT * 4 * 2 + 512 * 4 * 2;
    if (ws_size >= NEED) {
        _Float16* bank16 = (_Float16*)d_ws;
        _Float16* feat16 = bank16 + BANK_PAD_E;
        float* pm = (float*)(feat16 + FEAT_E);
        float* ps = pm + 512 * NT;
        float* tv = ps + 512 * NT;
        float* rl = tv + 512;
        k_cvt<<<dim3(2048), 256, 0, stream>>>(feat, bank, bank16);
        k_gemm16<<<dim3(4 * NT), 256, 0, stream>>>(feat16, bank16, gt, pm, ps, tv);
        k_rowlse<<<dim3(512), 128, 0, stream>>>(pm, ps, tv, rl);
        k_final<<<dim3(1), 512, 0, stream>>>(rl, (float*)d_out);
    } else {
        float* pm = (float*)d_ws;
        float* ps = pm + 512 * NT;
        float* tv = ps + 512 * NT;
        float* rl = tv + 512;
        k_gemm_lse<<<dim3(4 * NT), 512, 0, stream>>>(feat, bank, gt, pm, ps, tv);
        k_rowlse<<<dim3(512), 128, 0, stream>>>(pm, ps, tv, rl);
        k_final<<<dim3(1), 512, 0, stream>>>(rl, (float*)d_out);
    }
}